// Round 6
// baseline (1480.293 us; speedup 1.0000x reference)
//
#include <hip/hip_runtime.h>

#define SS 1024
#define FF 64
#define NG 256   // 4H gate columns
#define RT 512   // rec kernel threads (8 waves)
#define XT 256   // xz kernel threads (4 waves)

__device__ __forceinline__ float sigmoidf_(float x) {
    return __builtin_amdgcn_rcpf(1.0f + __expf(-x));
}
__device__ __forceinline__ float tanhf_(float x) {
    return 1.0f - 2.0f * __builtin_amdgcn_rcpf(__expf(2.0f * x) + 1.0f);
}

// lgkm-only barrier: does NOT drain vmcnt, so global prefetches stay in flight
// across step boundaries (a __syncthreads would emit vmcnt(0)).
#define RAW_BARRIER() asm volatile("s_waitcnt lgkmcnt(0)\n\ts_barrier" ::: "memory")

// ================= Kernel 1: xz = x @ Wx + bias =================
// Wk in LDS (64 KB, natural k-major: wkL[k*256+g] -> consecutive lanes hit
// consecutive banks, conflict-free). Each wave owns 32 rows; each thread
// covers 4 columns (lane, +64, +128, +192). x row element held per-lane,
// broadcast by constant-index readlane (VALU, no LDS).
__global__ __launch_bounds__(XT, 2)
void xz_gemm(const float* __restrict__ x, const float* __restrict__ wk,
             const float* __restrict__ bias, float* __restrict__ xz,
             int t0, int cs_shift) {
    const int tid  = threadIdx.x;
    const int lane = tid & 63;
    const int wave = tid >> 6;

    __shared__ float wkL[64 * NG];              // 64 KB
    {
        const float4* __restrict__ src = (const float4*)wk;
        float4* __restrict__ dst = (float4*)wkL;
#pragma unroll
        for (int i = 0; i < 16; ++i) dst[i * XT + tid] = src[i * XT + tid];
    }
    __syncthreads();

    const float b0 = bias[lane];
    const float b1 = bias[lane + 64];
    const float b2 = bias[lane + 128];
    const float b3 = bias[lane + 192];

    const int row0 = blockIdx.x * 128 + wave * 32;       // row within chunk
    const int bb   = row0 >> cs_shift;                   // batch element
    const int tl   = row0 & ((1 << cs_shift) - 1);       // step within chunk
    const int* __restrict__ xrow =
        (const int*)(x + ((size_t)bb * SS + t0 + tl) * FF);
    float* __restrict__ orow = xz + (size_t)row0 * NG;

    int xr[2][8];
#pragma unroll
    for (int j = 0; j < 8; ++j) xr[0][j] = xrow[j * FF + lane];

    for (int rg = 0; rg < 4; ++rg) {
        const int cur = rg & 1;
        if (rg < 3) {                                     // prefetch next group
#pragma unroll
            for (int j = 0; j < 8; ++j)
                xr[cur ^ 1][j] = xrow[(rg * 8 + 8 + j) * FF + lane];
        }
#pragma unroll
        for (int j = 0; j < 8; ++j) {
            float a0 = b0, a1 = b1, a2 = b2, a3 = b3;
            const int xv = xr[cur][j];
#pragma unroll
            for (int k = 0; k < 64; ++k) {
                const float s = __int_as_float(__builtin_amdgcn_readlane(xv, k));
                a0 = __builtin_fmaf(s, wkL[k * NG + lane],       a0);
                a1 = __builtin_fmaf(s, wkL[k * NG + lane + 64],  a1);
                a2 = __builtin_fmaf(s, wkL[k * NG + lane + 128], a2);
                a3 = __builtin_fmaf(s, wkL[k * NG + lane + 192], a3);
            }
            float* __restrict__ o = orow + (size_t)(rg * 8 + j) * NG;
            o[lane] = a0; o[lane + 64] = a1; o[lane + 128] = a2; o[lane + 192] = a3;
        }
    }
}

// ================= Kernel 2: recurrence =================
// wh rows 0..59 in LDS (60 KB) + rows 60..63 in 4 scalars per thread, so
// whL + zbuf = exactly 64 KB. h broadcast: one __shfl rotation per step, then
// constant-index readlanes. Thread (g=tid&255, half=tid>=256) does k-half of
// column g; partials combined via double-buffered zbuf, ONE lgkm-only barrier
// per step; all 8 waves redundantly compute per-lane h,c.
#define FH4(K) \
    a0 += __int_as_float(__builtin_amdgcn_readlane(hrot, (K) + 0)) * whp[((K) + 0) * NG]; \
    a1 += __int_as_float(__builtin_amdgcn_readlane(hrot, (K) + 1)) * whp[((K) + 1) * NG]; \
    a2 += __int_as_float(__builtin_amdgcn_readlane(hrot, (K) + 2)) * whp[((K) + 2) * NG]; \
    a3 += __int_as_float(__builtin_amdgcn_readlane(hrot, (K) + 3)) * whp[((K) + 3) * NG];

#define RSTEP(TL, P) do {                                                      \
    const int bsel = (TL) & 1;                                                 \
    float a0 = ld ? (P) : 0.0f, a1 = 0.0f, a2 = 0.0f, a3 = 0.0f;               \
    const int hb   = __float_as_int(h);                                        \
    const int hrot = __shfl(hb, rotidx, 64);   /* hrot[l] = h[(l+kofs)&63] */  \
    FH4(0) FH4(4) FH4(8) FH4(12) FH4(16) FH4(20) FH4(24)                       \
    if (ld) {                                  /* rows 28..31 from LDS */      \
        FH4(28)                                                                \
    } else {                                   /* rows 60..63 from regs */     \
        a0 += __int_as_float(__builtin_amdgcn_readlane(hrot, 28)) * wr0;       \
        a1 += __int_as_float(__builtin_amdgcn_readlane(hrot, 29)) * wr1;       \
        a2 += __int_as_float(__builtin_amdgcn_readlane(hrot, 30)) * wr2;       \
        a3 += __int_as_float(__builtin_amdgcn_readlane(hrot, 31)) * wr3;       \
    }                                                                          \
    zbuf[bsel][tid] = (a0 + a1) + (a2 + a3);                                   \
    RAW_BARRIER();                                                             \
    const float zi = zbuf[bsel][lane]       + zbuf[bsel][256 + lane];          \
    const float zf = zbuf[bsel][64 + lane]  + zbuf[bsel][320 + lane];          \
    const float zc = zbuf[bsel][128 + lane] + zbuf[bsel][384 + lane];          \
    const float zo = zbuf[bsel][192 + lane] + zbuf[bsel][448 + lane];          \
    const float ig = sigmoidf_(zi);                                            \
    const float fg = sigmoidf_(zf);                                            \
    const float og = sigmoidf_(zo);                                            \
    c = fg * c + ig * tanhf_(zc);                                              \
    h = og * tanhf_(c);                                                        \
    if (ld) {                                  /* refill xz prefetch slot */   \
        const int tn = ((TL) + 4 < CS) ? (TL) + 4 : (CS - 1);                  \
        P = xzb[(size_t)tn * NG];                                              \
    }                                                                          \
    if ((tid >> 6) == 0) {                     /* fused dense + sigmoid */     \
        float r = h * dwl;                                                     \
        r += __shfl_xor(r, 32, 64); r += __shfl_xor(r, 16, 64);                \
        r += __shfl_xor(r, 8, 64);  r += __shfl_xor(r, 4, 64);                 \
        r += __shfl_xor(r, 2, 64);  r += __shfl_xor(r, 1, 64);                 \
        if (lane == 0) outb[TL] = sigmoidf_(r + db0);                          \
    }                                                                          \
} while (0)

__global__ __launch_bounds__(RT, 2)
void lstm_rec(const float* __restrict__ xz, const float* __restrict__ rk,
              const float* __restrict__ dw, const float* __restrict__ db,
              float* __restrict__ out, float* __restrict__ state,
              int t0, int CS, int init) {
    const int b    = blockIdx.x;
    const int tid  = threadIdx.x;
    const int lane = tid & 63;
    const int g    = tid & 255;
    const bool ld  = (tid < 256);                 // lower k-half owns xz+bias
    const int kofs = ld ? 0 : 32;
    const int rotidx = (lane + kofs) & 63;

    __shared__ float whL[60 * NG];                // 60 KB, rows 0..59
    __shared__ float zbuf[2][RT];                 // 4 KB  -> total 64 KB
    {
        const float2* __restrict__ src = (const float2*)rk;
        float2* __restrict__ dst = (float2*)whL;
#pragma unroll
        for (int i = 0; i < 15; ++i) dst[i * RT + tid] = src[i * RT + tid];
    }
    const float wr0 = rk[60 * NG + g];
    const float wr1 = rk[61 * NG + g];
    const float wr2 = rk[62 * NG + g];
    const float wr3 = rk[63 * NG + g];

    const float dwl = dw[lane];
    const float db0 = db[0];

    float* __restrict__ sh = state;               // [256][64]
    float* __restrict__ sc = state + 256 * 64;
    float h, c;
    if (init) { h = 0.0f; c = 0.0f; }
    else      { h = sh[b * 64 + lane]; c = sc[b * 64 + lane]; }

    const float* __restrict__ whp  = whL + kofs * NG + g;   // imm offsets k*1024B
    const float* __restrict__ xzb  = xz + (size_t)b * CS * NG + g;
    float* __restrict__       outb = out + (size_t)b * SS + t0;

    __syncthreads();                              // whL staged

    float p0 = 0.0f, p1 = 0.0f, p2 = 0.0f, p3 = 0.0f;
    if (ld) { p0 = xzb[0]; p1 = xzb[NG]; p2 = xzb[2 * NG]; p3 = xzb[3 * NG]; }

    for (int tl = 0; tl < CS; tl += 4) {
        RSTEP(tl,     p0);
        RSTEP(tl + 1, p1);
        RSTEP(tl + 2, p2);
        RSTEP(tl + 3, p3);
    }

    if (tid < 64) { sh[b * 64 + tid] = h; sc[b * 64 + tid] = c; }
}

// ================= Host =================
extern "C" void kernel_launch(void* const* d_in, const int* in_sizes, int n_in,
                              void* d_out, int out_size, void* d_ws, size_t ws_size,
                              hipStream_t stream) {
    const float* x    = (const float*)d_in[0];
    const float* wk   = (const float*)d_in[1];
    const float* rk   = (const float*)d_in[2];
    const float* bias = (const float*)d_in[3];
    const float* dw   = (const float*)d_in[4];
    const float* db   = (const float*)d_in[5];
    float* out = (float*)d_out;

    const size_t stateBytes = 2ull * 256 * 64 * sizeof(float);   // 128 KB
    // Pick largest chunk CS that fits ws. Round 4 proved CS=128 (32 MB) fits.
    int cs_shift = 7;
    for (int s = 10; s >= 7; --s) {
        const size_t need = stateBytes + (((size_t)256 << s) * NG) * sizeof(float);
        if (need <= ws_size) { cs_shift = s; break; }
    }
    const int CS = 1 << cs_shift;

    float* state = (float*)d_ws;
    float* xzbuf = (float*)((char*)d_ws + stateBytes);

    for (int t0 = 0; t0 < SS; t0 += CS) {
        hipLaunchKernelGGL(xz_gemm, dim3(2 * CS), dim3(XT), 0, stream,
                           x, wk, bias, xzbuf, t0, cs_shift);
        hipLaunchKernelGGL(lstm_rec, dim3(256), dim3(RT), 0, stream,
                           xzbuf, rk, dw, db, out, state, t0, CS, (t0 == 0) ? 1 : 0);
    }
}

// Round 7
// 888.385 us; speedup vs baseline: 1.6663x; 1.6663x over previous
//
#include <hip/hip_runtime.h>

typedef __attribute__((ext_vector_type(8))) short short8;
typedef __attribute__((ext_vector_type(4))) float f32x4;

#define SS 1024
#define NB 16           // blocks (one per 16-batch tile)

__device__ __forceinline__ float sigmoidf_(float x) {
    return __builtin_amdgcn_rcpf(1.0f + __expf(-x));
}
__device__ __forceinline__ float tanhf_(float x) {
    return 1.0f - 2.0f * __builtin_amdgcn_rcpf(__expf(2.0f * x) + 1.0f);
}
__device__ __forceinline__ unsigned short f2bf(float f) {   // RNE f32->bf16
    unsigned int u = __float_as_uint(f);
    u += 0x7fffu + ((u >> 16) & 1u);
    return (unsigned short)(u >> 16);
}
__device__ __forceinline__ float bf2f(unsigned short s) {
    return __uint_as_float(((unsigned int)s) << 16);
}

// lgkm-only barrier: x prefetch (vmcnt) stays in flight across steps.
#define RAW_BARRIER() asm volatile("s_waitcnt lgkmcnt(0)\n\ts_barrier" ::: "memory")

// ============ Kernel 1: x -> bf16 A-fragment-ordered buffer ============
// Chunk gid = (bb*1024+t)*64 + m*4 + q holds 16 bf16: x[bb*16+m][t][q*8+j]
// (j=0..7) then x[..][32+q*8+j] — exactly the two A-frags lane (m + 16q)
// of the rec kernel needs for k-chunks 2,3.
__global__ __launch_bounds__(256)
void xconv(const float* __restrict__ x, short* __restrict__ xA) {
    const int gid = blockIdx.x * 256 + threadIdx.x;
    const int q  = gid & 3;
    const int m  = (gid >> 2) & 15;
    const int bt = gid >> 6;                 // bb*1024 + t
    const int t  = bt & 1023;
    const int bb = bt >> 10;
    const float* __restrict__ xr = x + (((size_t)(bb * 16 + m)) * SS + t) * 64;
    short8 o0, o1;
#pragma unroll
    for (int j = 0; j < 8; ++j) o0[j] = (short)f2bf(xr[q * 8 + j]);
#pragma unroll
    for (int j = 0; j < 8; ++j) o1[j] = (short)f2bf(xr[32 + q * 8 + j]);
    short8* __restrict__ op = (short8*)xA + (size_t)gid * 2;
    op[0] = o0; op[1] = o1;
}

// ============ Kernel 2: fused LSTM recurrence via MFMA ============
// z(16x256) = [h|x](16x128) @ [[rk],[wk]](128x256), per step, per block.
// B-frags (weights) live in 16 short8 registers per lane. C/D layout
// (verified m89): col=lane&15, row=(lane>>4)*4+reg. A: m=lane&15,
// k=(lane>>4)*8+j. B: n=lane&15, k=(lane>>4)*8+j.
#define MF(A, Bv, C) __builtin_amdgcn_mfma_f32_16x16x32_bf16(A, Bv, C, 0, 0, 0)

#define LOADB(VAR, G, KC) do {                                                \
    const float* __restrict__ Wsrc = ((KC) < 2) ? rk : wk;                    \
    const int kb = (((KC) & 1) << 5) + (q << 3);                              \
    const int nn = ((G) << 6) + n0;                                           \
    short8 v;                                                                 \
    v[0] = (short)f2bf(Wsrc[(kb + 0) * 256 + nn]);                            \
    v[1] = (short)f2bf(Wsrc[(kb + 1) * 256 + nn]);                            \
    v[2] = (short)f2bf(Wsrc[(kb + 2) * 256 + nn]);                            \
    v[3] = (short)f2bf(Wsrc[(kb + 3) * 256 + nn]);                            \
    v[4] = (short)f2bf(Wsrc[(kb + 4) * 256 + nn]);                            \
    v[5] = (short)f2bf(Wsrc[(kb + 5) * 256 + nn]);                            \
    v[6] = (short)f2bf(Wsrc[(kb + 6) * 256 + nn]);                            \
    v[7] = (short)f2bf(Wsrc[(kb + 7) * 256 + nn]);                            \
    VAR = v; } while (0)

// hbuf row stride 72 bf16 (144 B, 16B-aligned rows; A-frag b128 reads land
// 8 lanes per bank-quad = the natural full-BW pattern).
#define HROW 72

#define GREG(R) {                                                             \
    const float ig = sigmoidf_(zi[R]);                                        \
    const float fg = sigmoidf_(zf[R]);                                        \
    const float og = sigmoidf_(zo[R]);                                        \
    cc##R = fg * cc##R + ig * tanhf_(zc[R]);                                  \
    const float hv = og * tanhf_(cc##R);                                      \
    hbuf[wb][((q << 2) + R) * HROW + n0] = (short)f2bf(hv); }

#define DENSE(RB, TOUT) {                                                     \
    const uint2 hh = *(const uint2*)&hbuf[RB][row_d * HROW + (m << 2)];       \
    float p = bf2f((unsigned short)hh.x)         * dw4.x                      \
            + bf2f((unsigned short)(hh.x >> 16)) * dw4.y                      \
            + bf2f((unsigned short)hh.y)         * dw4.z                      \
            + bf2f((unsigned short)(hh.y >> 16)) * dw4.w;                     \
    p += __shfl_xor(p, 1, 64); p += __shfl_xor(p, 2, 64);                     \
    p += __shfl_xor(p, 4, 64); p += __shfl_xor(p, 8, 64);                     \
    if (m == 0) out[(size_t)(((bb << 4) + row_d) << 10) + (TOUT)] =           \
        sigmoidf_(p + db0); }

#define XOFF(T) ((((size_t)((bb << 10) | (T))) * 64 + ((m << 2) | q)) * 2)

#define STEP(T, X0, X1) do {                                                  \
    const int rb = (T) & 1, wb = rb ^ 1;                                      \
    if ((T) > 0) DENSE(rb, (T) - 1);                                          \
    const short8 ha0 = *(const short8*)&hbuf[rb][m * HROW + (q << 3)];        \
    const short8 ha1 = *(const short8*)&hbuf[rb][m * HROW + 32 + (q << 3)];   \
    f32x4 zi = MF(ha0, B00, ((f32x4){bs0, bs0, bs0, bs0}));                   \
    zi = MF(ha1, B01, zi); zi = MF(X0, B02, zi); zi = MF(X1, B03, zi);        \
    f32x4 zf = MF(ha0, B10, ((f32x4){bs1, bs1, bs1, bs1}));                   \
    zf = MF(ha1, B11, zf); zf = MF(X0, B12, zf); zf = MF(X1, B13, zf);        \
    f32x4 zc = MF(ha0, B20, ((f32x4){bs2, bs2, bs2, bs2}));                   \
    zc = MF(ha1, B21, zc); zc = MF(X0, B22, zc); zc = MF(X1, B23, zc);        \
    f32x4 zo = MF(ha0, B30, ((f32x4){bs3, bs3, bs3, bs3}));                   \
    zo = MF(ha1, B31, zo); zo = MF(X0, B32, zo); zo = MF(X1, B33, zo);        \
    {   /* refill this x slot for T+2; load stays in flight past barrier */   \
        const size_t o = XOFF(((T) + 2 < SS) ? (T) + 2 : SS - 1);             \
        X0 = xp[o]; X1 = xp[o + 1];                                           \
    }                                                                         \
    GREG(0) GREG(1) GREG(2) GREG(3)                                           \
    RAW_BARRIER();                                                            \
} while (0)

__global__ __launch_bounds__(256, 1)
void lstm_mfma(const short* __restrict__ xA, const float* __restrict__ wk,
               const float* __restrict__ rk, const float* __restrict__ bias,
               const float* __restrict__ dw, const float* __restrict__ db,
               float* __restrict__ out) {
    const int bb  = blockIdx.x;
    const int tid = threadIdx.x;
    const int l   = tid & 63;
    const int w   = tid >> 6;        // wave: hcol slice [16w,16w+16)
    const int m   = l & 15;          // batch row within tile (A/C row)
    const int q   = l >> 4;
    const int n0  = (w << 4) + m;    // per-gate column offset (and h col)
    const int row_d = (w << 2) + q;  // dense-output batch row for this lane

    // 16 weight B-frags, register-resident
    short8 B00, B01, B02, B03, B10, B11, B12, B13;
    short8 B20, B21, B22, B23, B30, B31, B32, B33;
    LOADB(B00, 0, 0); LOADB(B01, 0, 1); LOADB(B02, 0, 2); LOADB(B03, 0, 3);
    LOADB(B10, 1, 0); LOADB(B11, 1, 1); LOADB(B12, 1, 2); LOADB(B13, 1, 3);
    LOADB(B20, 2, 0); LOADB(B21, 2, 1); LOADB(B22, 2, 2); LOADB(B23, 2, 3);
    LOADB(B30, 3, 0); LOADB(B31, 3, 1); LOADB(B32, 3, 2); LOADB(B33, 3, 3);

    const float bs0 = bias[n0];
    const float bs1 = bias[64 + n0];
    const float bs2 = bias[128 + n0];
    const float bs3 = bias[192 + n0];
    const float4 dw4 = *(const float4*)(dw + (m << 2));
    const float db0 = db[0];

    __shared__ short hbuf[2][16 * HROW];
    for (int i = tid; i < 2 * 16 * HROW; i += 256) ((short*)hbuf)[i] = 0;
    __syncthreads();

    const short8* __restrict__ xp = (const short8*)xA;
    short8 xa0 = xp[XOFF(0)], xa1 = xp[XOFF(0) + 1];
    short8 xb0 = xp[XOFF(1)], xb1 = xp[XOFF(1) + 1];

    float cc0 = 0.0f, cc1 = 0.0f, cc2 = 0.0f, cc3 = 0.0f;

    for (int t = 0; t < SS; t += 2) {
        STEP(t,     xa0, xa1);
        STEP(t + 1, xb0, xb1);
    }
    // epilogue: dense output for t = SS-1 (h_{SS-1} is in hbuf[0])
    DENSE(0, SS - 1);
}

// ============ Host ============
extern "C" void kernel_launch(void* const* d_in, const int* in_sizes, int n_in,
                              void* d_out, int out_size, void* d_ws, size_t ws_size,
                              hipStream_t stream) {
    const float* x    = (const float*)d_in[0];
    const float* wk   = (const float*)d_in[1];
    const float* rk   = (const float*)d_in[2];
    const float* bias = (const float*)d_in[3];
    const float* dw   = (const float*)d_in[4];
    const float* db   = (const float*)d_in[5];
    float* out = (float*)d_out;

    short* xA = (short*)d_ws;   // 16*1024*64 chunks * 32 B = 33.5 MB

    hipLaunchKernelGGL(xconv, dim3(NB * 1024 * 64 / 256), dim3(256), 0, stream,
                       x, xA);
    hipLaunchKernelGGL(lstm_mfma, dim3(NB), dim3(256), 0, stream,
                       xA, wk, rk, bias, dw, db, out);
}

// Round 8
// 824.060 us; speedup vs baseline: 1.7963x; 1.0781x over previous
//
#include <hip/hip_runtime.h>

typedef __attribute__((ext_vector_type(8))) short short8;
typedef __attribute__((ext_vector_type(4))) float f32x4;
typedef __attribute__((ext_vector_type(4))) short short4v;

#define SS 1024
#define NB 16
#define HROW 72     // bf16 elems per hbuf row (144 B, 16B-aligned)
#define ZROW 68     // f32 elems per zx row (+4 pad)

__device__ __forceinline__ float sigmoidf_(float x) {
    return __builtin_amdgcn_rcpf(1.0f + __expf(-x));
}
__device__ __forceinline__ float tanhf_(float x) {
    return 1.0f - 2.0f * __builtin_amdgcn_rcpf(__expf(2.0f * x) + 1.0f);
}
__device__ __forceinline__ unsigned short f2bf(float f) {   // RNE f32->bf16
    unsigned int u = __float_as_uint(f);
    u += 0x7fffu + ((u >> 16) & 1u);
    return (unsigned short)(u >> 16);
}

// lgkm-only barrier: global (vmcnt) prefetches stay in flight across it.
#define RAW_BARRIER() asm volatile("s_waitcnt lgkmcnt(0)\n\ts_barrier" ::: "memory")

// ============ Kernel 1: x -> bf16 A-fragment-ordered buffer (unchanged) ====
__global__ __launch_bounds__(256)
void xconv(const float* __restrict__ x, short* __restrict__ xA) {
    const int gid = blockIdx.x * 256 + threadIdx.x;
    const int q  = gid & 3;
    const int m  = (gid >> 2) & 15;
    const int bt = gid >> 6;                 // bb*1024 + t
    const int t  = bt & 1023;
    const int bb = bt >> 10;
    const float* __restrict__ xr = x + (((size_t)(bb * 16 + m)) * SS + t) * 64;
    short8 o0, o1;
#pragma unroll
    for (int j = 0; j < 8; ++j) o0[j] = (short)f2bf(xr[q * 8 + j]);
#pragma unroll
    for (int j = 0; j < 8; ++j) o1[j] = (short)f2bf(xr[32 + q * 8 + j]);
    short8* __restrict__ op = (short8*)xA + (size_t)gid * 2;
    op[0] = o0; op[1] = o1;
}

// ============ Kernel 2: 2-stage pipelined LSTM (A: MFMA, B: gates) =========
#define MF(A, Bv, C) __builtin_amdgcn_mfma_f32_16x16x32_bf16(A, Bv, C, 0, 0, 0)

#define LOADB(VAR, G, KC) do {                                                \
    const float* __restrict__ Wsrc = ((KC) < 2) ? rk : wk;                    \
    const int kb = (((KC) & 1) << 5) + (q << 3);                              \
    const int nn = ((G) << 6) + n0;                                           \
    short8 v;                                                                 \
    v[0] = (short)f2bf(Wsrc[(kb + 0) * 256 + nn]);                            \
    v[1] = (short)f2bf(Wsrc[(kb + 1) * 256 + nn]);                            \
    v[2] = (short)f2bf(Wsrc[(kb + 2) * 256 + nn]);                            \
    v[3] = (short)f2bf(Wsrc[(kb + 3) * 256 + nn]);                            \
    v[4] = (short)f2bf(Wsrc[(kb + 4) * 256 + nn]);                            \
    v[5] = (short)f2bf(Wsrc[(kb + 5) * 256 + nn]);                            \
    v[6] = (short)f2bf(Wsrc[(kb + 6) * 256 + nn]);                            \
    v[7] = (short)f2bf(Wsrc[(kb + 7) * 256 + nn]);                            \
    VAR = v; } while (0)

#define XOFF(T) ((((size_t)((bb << 10) | (T))) * 64 + ((m << 2) | q)) * 2)

// A-wave body for step T (parity CUR = T&1). Consumes xq* (xpart for T),
// produces z_T in zx[CUR]; then computes xpart for T+1 from XN and refills
// the XC slot with x_{T+2} (stays in flight across barriers).
#define ABODY(T, CUR, XC0, XC1, XN0, XN1) do {                                 \
    const short8 ha0 = *(const short8*)&hbuf[(CUR) ^ 1][m * HROW + (q << 3)];  \
    const short8 ha1 = *(const short8*)&hbuf[(CUR) ^ 1][m * HROW + 32 + (q << 3)]; \
    f32x4 z0 = MF(ha1, BH01, MF(ha0, BH00, xq0));                              \
    f32x4 z1 = MF(ha1, BH11, MF(ha0, BH10, xq1));                              \
    f32x4 z2 = MF(ha1, BH21, MF(ha0, BH20, xq2));                              \
    f32x4 z3 = MF(ha1, BH31, MF(ha0, BH30, xq3));                              \
    zx[CUR][0][(q << 2) + 0][n0] = z0[0]; zx[CUR][0][(q << 2) + 1][n0] = z0[1];\
    zx[CUR][0][(q << 2) + 2][n0] = z0[2]; zx[CUR][0][(q << 2) + 3][n0] = z0[3];\
    zx[CUR][1][(q << 2) + 0][n0] = z1[0]; zx[CUR][1][(q << 2) + 1][n0] = z1[1];\
    zx[CUR][1][(q << 2) + 2][n0] = z1[2]; zx[CUR][1][(q << 2) + 3][n0] = z1[3];\
    zx[CUR][2][(q << 2) + 0][n0] = z2[0]; zx[CUR][2][(q << 2) + 1][n0] = z2[1];\
    zx[CUR][2][(q << 2) + 2][n0] = z2[2]; zx[CUR][2][(q << 2) + 3][n0] = z2[3];\
    zx[CUR][3][(q << 2) + 0][n0] = z3[0]; zx[CUR][3][(q << 2) + 1][n0] = z3[1];\
    zx[CUR][3][(q << 2) + 2][n0] = z3[2]; zx[CUR][3][(q << 2) + 3][n0] = z3[3];\
    RAW_BARRIER();  /* z_T ready */                                            \
    if ((T) > 0 && w == 0 && l < 16) {   /* dense finalize for step T-1 */     \
        const float s = pbuf[(CUR) ^ 1][l]      + pbuf[(CUR) ^ 1][16 + l]      \
                      + pbuf[(CUR) ^ 1][32 + l] + pbuf[(CUR) ^ 1][48 + l];     \
        out[(size_t)(((bb << 4) + l) << 10) + (T) - 1] = sigmoidf_(s + db0);   \
    }                                                                          \
    xq0 = MF(XN1, BX01, MF(XN0, BX00, cb0));                                   \
    xq1 = MF(XN1, BX11, MF(XN0, BX10, cb1));                                   \
    xq2 = MF(XN1, BX21, MF(XN0, BX20, cb2));                                   \
    xq3 = MF(XN1, BX31, MF(XN0, BX30, cb3));                                   \
    { const size_t o = XOFF(((T) + 2 < SS) ? (T) + 2 : SS - 1);                \
      XC0 = xsrc[o]; XC1 = xsrc[o + 1]; }                                      \
    RAW_BARRIER();  /* h_T will be ready next iter */                          \
} while (0)

// B-wave body for parity CUR: read z (4x b128), gates, h -> hbuf (A-frag
// bf16 layout), dense partials -> pbuf.
#define BBODY(TT, CUR) do {                                                    \
    RAW_BARRIER();  /* z ready */                                              \
    const f32x4 vzi = *(const f32x4*)&zx[CUR][0][r][c0];                       \
    const f32x4 vzf = *(const f32x4*)&zx[CUR][1][r][c0];                       \
    const f32x4 vzc = *(const f32x4*)&zx[CUR][2][r][c0];                       \
    const f32x4 vzo = *(const f32x4*)&zx[CUR][3][r][c0];                       \
    float h0, h1, h2, h3;                                                      \
    { const float ig = sigmoidf_(vzi[0]), fg = sigmoidf_(vzf[0]),              \
                  og = sigmoidf_(vzo[0]);                                      \
      cc0 = fg * cc0 + ig * tanhf_(vzc[0]); h0 = og * tanhf_(cc0); }           \
    { const float ig = sigmoidf_(vzi[1]), fg = sigmoidf_(vzf[1]),              \
                  og = sigmoidf_(vzo[1]);                                      \
      cc1 = fg * cc1 + ig * tanhf_(vzc[1]); h1 = og * tanhf_(cc1); }           \
    { const float ig = sigmoidf_(vzi[2]), fg = sigmoidf_(vzf[2]),              \
                  og = sigmoidf_(vzo[2]);                                      \
      cc2 = fg * cc2 + ig * tanhf_(vzc[2]); h2 = og * tanhf_(cc2); }           \
    { const float ig = sigmoidf_(vzi[3]), fg = sigmoidf_(vzf[3]),              \
                  og = sigmoidf_(vzo[3]);                                      \
      cc3 = fg * cc3 + ig * tanhf_(vzc[3]); h3 = og * tanhf_(cc3); }           \
    short4v hp;                                                                \
    hp[0] = (short)f2bf(h0); hp[1] = (short)f2bf(h1);                          \
    hp[2] = (short)f2bf(h2); hp[3] = (short)f2bf(h3);                          \
    *(short4v*)&hbuf[CUR][r * HROW + c0] = hp;                                 \
    float p = h0 * dwv.x + h1 * dwv.y + h2 * dwv.z + h3 * dwv.w;               \
    p += __shfl_xor(p, 16, 64); p += __shfl_xor(p, 32, 64);                    \
    if (u == 0) pbuf[CUR][(vp << 4) + r] = p;                                  \
    RAW_BARRIER();  /* h ready */                                              \
} while (0)

__global__ __launch_bounds__(512, 1)
void lstm_pipe(const short* __restrict__ xA, const float* __restrict__ wk,
               const float* __restrict__ rk, const float* __restrict__ bias,
               const float* __restrict__ dw, const float* __restrict__ db,
               float* __restrict__ out) {
    const int bb  = blockIdx.x;
    const int tid = threadIdx.x;
    const int l   = tid & 63;
    const int w   = tid >> 6;

    __shared__ float zx[2][4][16][ZROW];      // 34.8 KB
    __shared__ short hbuf[2][16 * HROW];      // 4.6 KB
    __shared__ float pbuf[2][64];             // 0.5 KB

    for (int i = tid; i < 2 * 16 * HROW; i += 512) ((short*)hbuf)[i] = 0;
    __syncthreads();

    if (w < 4) {
        // ---------------- A-group: MFMA producer ----------------
        const int m  = l & 15;
        const int q  = l >> 4;
        const int n0 = (w << 4) + m;

        short8 BH00, BH01, BH10, BH11, BH20, BH21, BH30, BH31;
        short8 BX00, BX01, BX10, BX11, BX20, BX21, BX30, BX31;
        LOADB(BH00, 0, 0); LOADB(BH01, 0, 1); LOADB(BX00, 0, 2); LOADB(BX01, 0, 3);
        LOADB(BH10, 1, 0); LOADB(BH11, 1, 1); LOADB(BX10, 1, 2); LOADB(BX11, 1, 3);
        LOADB(BH20, 2, 0); LOADB(BH21, 2, 1); LOADB(BX20, 2, 2); LOADB(BX21, 2, 3);
        LOADB(BH30, 3, 0); LOADB(BH31, 3, 1); LOADB(BX30, 3, 2); LOADB(BX31, 3, 3);

        const float b0 = bias[n0], b1 = bias[64 + n0];
        const float b2 = bias[128 + n0], b3 = bias[192 + n0];
        const f32x4 cb0 = {b0, b0, b0, b0};
        const f32x4 cb1 = {b1, b1, b1, b1};
        const f32x4 cb2 = {b2, b2, b2, b2};
        const f32x4 cb3 = {b3, b3, b3, b3};
        const float db0 = db[0];

        const short8* __restrict__ xsrc = (const short8*)xA;
        short8 Xa0 = xsrc[XOFF(0)], Xa1 = xsrc[XOFF(0) + 1];
        short8 Xb0 = xsrc[XOFF(1)], Xb1 = xsrc[XOFF(1) + 1];

        // xpart for t=0
        f32x4 xq0 = MF(Xa1, BX01, MF(Xa0, BX00, cb0));
        f32x4 xq1 = MF(Xa1, BX11, MF(Xa0, BX10, cb1));
        f32x4 xq2 = MF(Xa1, BX21, MF(Xa0, BX20, cb2));
        f32x4 xq3 = MF(Xa1, BX31, MF(Xa0, BX30, cb3));

        for (int t = 0; t < SS; t += 2) {
            ABODY(t,     0, Xa0, Xa1, Xb0, Xb1);
            ABODY(t + 1, 1, Xb0, Xb1, Xa0, Xa1);
        }
        if (w == 0 && l < 16) {        // dense finalize for t = SS-1
            const float s = pbuf[1][l] + pbuf[1][16 + l]
                          + pbuf[1][32 + l] + pbuf[1][48 + l];
            out[(size_t)(((bb << 4) + l) << 10) + SS - 1] = sigmoidf_(s + db0);
        }
    } else {
        // ---------------- B-group: gate consumer ----------------
        const int r  = l & 15;
        const int u  = l >> 4;
        const int vp = w - 4;
        const int c0 = (vp << 4) + (u << 2);
        const float4 dwv = *(const float4*)(dw + c0);
        float cc0 = 0.f, cc1 = 0.f, cc2 = 0.f, cc3 = 0.f;

        for (int t = 0; t < SS; t += 2) {
            BBODY(t,     0);
            BBODY(t + 1, 1);
        }
    }
}

// ============ Host ============
extern "C" void kernel_launch(void* const* d_in, const int* in_sizes, int n_in,
                              void* d_out, int out_size, void* d_ws, size_t ws_size,
                              hipStream_t stream) {
    const float* x    = (const float*)d_in[0];
    const float* wk   = (const float*)d_in[1];
    const float* rk   = (const float*)d_in[2];
    const float* bias = (const float*)d_in[3];
    const float* dw   = (const float*)d_in[4];
    const float* db   = (const float*)d_in[5];
    float* out = (float*)d_out;

    short* xA = (short*)d_ws;   // 16*1024*64 chunks * 32 B = 33.5 MB

    hipLaunchKernelGGL(xconv, dim3(NB * 1024 * 64 / 256), dim3(256), 0, stream,
                       x, xA);
    hipLaunchKernelGGL(lstm_pipe, dim3(NB), dim3(512), 0, stream,
                       xA, wk, rk, bias, dw, db, out);
}